// Round 8
// baseline (3128.406 us; speedup 1.0000x reference)
//
#include <hip/hip_runtime.h>

#define B_ 8
#define CIN_ 4
#define H_ 512
#define W_ 512
#define HID_ 32
#define NCLS_ 19
#define HO_ 256
#define WO_ 256
#define UP_ 512
#define NPLANE (B_*NCLS_)          // 152
#define PLANE_ELEMS (UP_*UP_)      // 262144
#define KMED1 131071u

// ---------- helpers ----------

__device__ __forceinline__ unsigned f2key(float f) {
  unsigned u = __float_as_uint(f);
  return (u & 0x80000000u) ? ~u : (u | 0x80000000u);
}
__device__ __forceinline__ float key2f(unsigned k) {
  unsigned u = (k & 0x80000000u) ? (k & 0x7FFFFFFFu) : ~k;
  return __uint_as_float(u);
}
__device__ __forceinline__ float ninf() { return __uint_as_float(0xFF800000u); }

// Bilinear upsample value (fmaf-pinned so all kernels agree bit-exactly).
__device__ __forceinline__ float up_val(const float* __restrict__ p, int oy, int ox) {
  const float s = (float)(255.0 / 511.0);
  float posy = (float)oy * s;
  int ly = (int)posy; if (ly > 254) ly = 254;
  float fy = posy - (float)ly;
  float posx = (float)ox * s;
  int lx = (int)posx; if (lx > 254) lx = 254;
  float fx = posx - (float)lx;
  const float* q = p + ly * WO_ + lx;
  float a = q[0], b = q[1], c = q[WO_], d = q[WO_ + 1];
  float r0 = fmaf(fx, b - a, a);
  float r1 = fmaf(fx, d - c, c);
  return fmaf(fy, r1 - r0, r0);
}

// ---------- conv1: (8,4,512,512) -> relu -> (8,32,256,256), stride 2, pad 1 ----------
// Round-6 configuration (reverted from the oc-split that caused 4x HBM
// amplification): 2 cols/thread, float2 acc[32], bounds(256,4), 1024 blocks.
__global__ __launch_bounds__(256, 4) void conv1_kernel(
    const float* __restrict__ x, const float* __restrict__ w1,
    const float* __restrict__ b1, float* __restrict__ h) {
  int t = threadIdx.x & 63;
  int r = threadIdx.x >> 6;
  int oh = blockIdx.x * 4 + r;
  int b  = blockIdx.z;
  int ow0 = blockIdx.y * 128 + t * 2;
  int ic0 = 2 * ow0;            // center input col of acc.x

  float2 acc[HID_];
  #pragma unroll
  for (int oc = 0; oc < HID_; ++oc) {
    float bb = b1[oc];
    acc[oc].x = bb; acc[oc].y = bb;
  }

  #pragma unroll
  for (int ci = 0; ci < CIN_; ++ci) {
    const float* xp = x + ((size_t)(b * CIN_ + ci)) * H_ * W_;
    float4 A0, A1, A2;
    float lm[3];
    #pragma unroll
    for (int kh = 0; kh < 3; ++kh) {
      int ih = 2 * oh + kh - 1;
      float4 Av; float lv = 0.f;
      if ((unsigned)ih < (unsigned)H_) {
        const float* row = xp + ih * W_;
        Av = *reinterpret_cast<const float4*>(row + ic0);
        lv = (ic0 > 0) ? row[ic0 - 1] : 0.f;
      } else {
        Av.x = 0.f; Av.y = 0.f; Av.z = 0.f; Av.w = 0.f;
      }
      if (kh == 0) A0 = Av; else if (kh == 1) A1 = Av; else A2 = Av;
      lm[kh] = lv;
    }
    #pragma unroll
    for (int oc = 0; oc < HID_; ++oc) {
      const float* wp = w1 + ((size_t)oc * CIN_ + ci) * 9;
      {
        float w0 = wp[0], w1v = wp[1], w2v = wp[2];
        acc[oc].x += w0 * lm[0] + w1v * A0.x + w2v * A0.y;
        acc[oc].y += w0 * A0.y  + w1v * A0.z + w2v * A0.w;
      }
      {
        float w0 = wp[3], w1v = wp[4], w2v = wp[5];
        acc[oc].x += w0 * lm[1] + w1v * A1.x + w2v * A1.y;
        acc[oc].y += w0 * A1.y  + w1v * A1.z + w2v * A1.w;
      }
      {
        float w0 = wp[6], w1v = wp[7], w2v = wp[8];
        acc[oc].x += w0 * lm[2] + w1v * A2.x + w2v * A2.y;
        acc[oc].y += w0 * A2.y  + w1v * A2.z + w2v * A2.w;
      }
    }
  }
  #pragma unroll
  for (int oc = 0; oc < HID_; ++oc) {
    float2 o;
    o.x = fmaxf(acc[oc].x, 0.f); o.y = fmaxf(acc[oc].y, 0.f);
    *reinterpret_cast<float2*>(h + (((size_t)(b * HID_ + oc) * HO_ + oh) * WO_ + ow0)) = o;
  }
}

// ---------- conv2: (8,32,256,256) -> (8,19,256,256), stride 1, pad 1 ----------
// Round-6 tiling (float2 acc[19], bounds(256,4), 1024 blocks) + software-
// pipelined ci loop: window(ci+1) loads issue BEFORE fma(ci) so each load has
// a full FMA block (~680 issue cycles) to complete. FP chain order unchanged.
__device__ __forceinline__ void c2_win(const float* __restrict__ hp, int oh, int ow0,
                                       float2& M0, float2& M1, float2& M2,
                                       float& L0, float& L1, float& L2,
                                       float& R0, float& R1, float& R2) {
  #pragma unroll
  for (int kh = 0; kh < 3; ++kh) {
    int ih = oh + kh - 1;
    float2 Mv; float lv = 0.f, rv = 0.f;
    if ((unsigned)ih < (unsigned)HO_) {
      const float* row = hp + ih * WO_;
      Mv = *reinterpret_cast<const float2*>(row + ow0);
      lv = (ow0 > 0) ? row[ow0 - 1] : 0.f;
      rv = (ow0 + 2 < WO_) ? row[ow0 + 2] : 0.f;
    } else { Mv.x = 0.f; Mv.y = 0.f; }
    if (kh == 0)      { M0 = Mv; L0 = lv; R0 = rv; }
    else if (kh == 1) { M1 = Mv; L1 = lv; R1 = rv; }
    else              { M2 = Mv; L2 = lv; R2 = rv; }
  }
}

__device__ __forceinline__ void c2_fma(float2* acc, const float* __restrict__ wpc,
                                       const float2& M0, const float2& M1, const float2& M2,
                                       float L0, float L1, float L2,
                                       float R0, float R1, float R2) {
  #pragma unroll
  for (int oc = 0; oc < NCLS_; ++oc) {
    const float* wp = wpc + (size_t)oc * (HID_ * 9);
    {
      float w0 = wp[0], w1v = wp[1], w2v = wp[2];
      acc[oc].x += w0 * L0   + w1v * M0.x + w2v * M0.y;
      acc[oc].y += w0 * M0.x + w1v * M0.y + w2v * R0;
    }
    {
      float w0 = wp[3], w1v = wp[4], w2v = wp[5];
      acc[oc].x += w0 * L1   + w1v * M1.x + w2v * M1.y;
      acc[oc].y += w0 * M1.x + w1v * M1.y + w2v * R1;
    }
    {
      float w0 = wp[6], w1v = wp[7], w2v = wp[8];
      acc[oc].x += w0 * L2   + w1v * M2.x + w2v * M2.y;
      acc[oc].y += w0 * M2.x + w1v * M2.y + w2v * R2;
    }
  }
}

__global__ __launch_bounds__(256, 4) void conv2_kernel(
    const float* __restrict__ h, const float* __restrict__ w2,
    const float* __restrict__ b2, float* __restrict__ c0) {
  int t = threadIdx.x & 63;
  int r = threadIdx.x >> 6;
  int oh = blockIdx.x * 4 + r;
  int b  = blockIdx.z;
  int ow0 = blockIdx.y * 128 + t * 2;

  float2 acc[NCLS_];
  #pragma unroll
  for (int oc = 0; oc < NCLS_; ++oc) {
    float bb = b2[oc];
    acc[oc].x = bb; acc[oc].y = bb;
  }

  const size_t plane = (size_t)HO_ * WO_;
  const float* hb = h + (size_t)b * HID_ * plane;

  float2 A0, A1, A2, B0, B1, B2;
  float AL0, AL1, AL2, AR0, AR1, AR2;
  float BL0, BL1, BL2, BR0, BR1, BR2;

  c2_win(hb, oh, ow0, A0, A1, A2, AL0, AL1, AL2, AR0, AR1, AR2);   // ci = 0
  #pragma unroll
  for (int ci = 0; ci < HID_; ci += 2) {
    c2_win(hb + (size_t)(ci + 1) * plane, oh, ow0,
           B0, B1, B2, BL0, BL1, BL2, BR0, BR1, BR2);              // prefetch ci+1
    c2_fma(acc, w2 + ci * 9, A0, A1, A2, AL0, AL1, AL2, AR0, AR1, AR2);
    if (ci + 2 < HID_)
      c2_win(hb + (size_t)(ci + 2) * plane, oh, ow0,
             A0, A1, A2, AL0, AL1, AL2, AR0, AR1, AR2);            // prefetch ci+2
    c2_fma(acc, w2 + (ci + 1) * 9, B0, B1, B2, BL0, BL1, BL2, BR0, BR1, BR2);
  }

  #pragma unroll
  for (int oc = 0; oc < NCLS_; ++oc) {
    *reinterpret_cast<float2*>(c0 + (((size_t)(b * NCLS_ + oc) * HO_ + oh) * WO_ + ow0)) = acc[oc];
  }
}

// ---------- upsample fused with median hist pass 1 ----------
// grid (8 chunks of 64 rows, 152 planes). Computes the bilinear plane, stores
// it, and histograms key>>21 (pass-1 fmask=0 -> unconditional) into the same
// wave-privatized LDS layout the standalone pass used. Eliminates one full
// 159 MB plane read + one launch; merge traffic unchanged (8x2048/plane).
__global__ __launch_bounds__(256) void upsample_hist_kernel(
    const float* __restrict__ c0, float* __restrict__ out,
    unsigned* __restrict__ ghist) {
  __shared__ unsigned lh[4 * 2048];
  int tid = threadIdx.x;
  int chunk = blockIdx.x;
  int plane = blockIdx.y;
  unsigned* mylh = lh + ((tid >> 6) << 11);
  for (int i = tid; i < 4 * 2048; i += 256) lh[i] = 0u;
  __syncthreads();
  const float* p = c0 + (size_t)plane * HO_ * WO_;
  float* op = out + (size_t)plane * PLANE_ELEMS;
  int ox0 = (tid & 127) * 4;
  #pragma unroll 2
  for (int it = 0; it < 32; ++it) {
    int oy = chunk * 64 + it * 2 + (tid >> 7);
    float4 o;
    o.x = up_val(p, oy, ox0 + 0);
    o.y = up_val(p, oy, ox0 + 1);
    o.z = up_val(p, oy, ox0 + 2);
    o.w = up_val(p, oy, ox0 + 3);
    *reinterpret_cast<float4*>(op + (size_t)oy * UP_ + ox0) = o;
    atomicAdd(&mylh[f2key(o.x) >> 21], 1u);
    atomicAdd(&mylh[f2key(o.y) >> 21], 1u);
    atomicAdd(&mylh[f2key(o.z) >> 21], 1u);
    atomicAdd(&mylh[f2key(o.w) >> 21], 1u);
  }
  __syncthreads();
  for (int i = tid; i < 2048; i += 256) {
    unsigned c = lh[i] + lh[2048 + i] + lh[4096 + i] + lh[6144 + i];
    if (c) atomicAdd(&ghist[(size_t)plane * 2048 + i], c);
  }
}

// ---------- median machinery: radix select over the materialized plane ----------

__global__ void init_kernel(unsigned* kArr, unsigned* pvalArr, unsigned* gbArr,
                            unsigned* flagArr) {
  int i = threadIdx.x;
  if (i < NPLANE) { kArr[i] = KMED1; pvalArr[i] = 0u; gbArr[i] = 0u; flagArr[i] = 0u; }
}

// Passes 2 & 3: coalesced float4 reads of the materialized plane (L3-hot).
__global__ __launch_bounds__(256) void hist_pass_kernel(
    const float* __restrict__ up, const unsigned* __restrict__ pvalArr,
    unsigned* __restrict__ ghist, int shift, unsigned bmask, unsigned fmask) {
  __shared__ unsigned lh[4 * 2048];
  int tid = threadIdx.x;
  int chunk = blockIdx.x;   // 8 chunks of 32768 elements
  int plane = blockIdx.y;
  unsigned* mylh = lh + ((tid >> 6) << 11);
  for (int i = tid; i < 4 * 2048; i += 256) lh[i] = 0u;
  __syncthreads();
  unsigned fval = pvalArr[plane] & fmask;
  const float4* p4 = reinterpret_cast<const float4*>(up + (size_t)plane * PLANE_ELEMS)
                     + (size_t)chunk * 8192;
  #pragma unroll 4
  for (int it = 0; it < 32; ++it) {
    float4 v = p4[it * 256 + tid];
    unsigned k0 = f2key(v.x), k1 = f2key(v.y), k2 = f2key(v.z), k3 = f2key(v.w);
    if ((k0 & fmask) == fval) atomicAdd(&mylh[(k0 >> shift) & bmask], 1u);
    if ((k1 & fmask) == fval) atomicAdd(&mylh[(k1 >> shift) & bmask], 1u);
    if ((k2 & fmask) == fval) atomicAdd(&mylh[(k2 >> shift) & bmask], 1u);
    if ((k3 & fmask) == fval) atomicAdd(&mylh[(k3 >> shift) & bmask], 1u);
  }
  __syncthreads();
  for (int i = tid; i < 2048; i += 256) {
    unsigned c = lh[i] + lh[2048 + i] + lh[4096 + i] + lh[6144 + i];
    if (c) atomicAdd(&ghist[(size_t)plane * 2048 + i], c);
  }
}

__global__ __launch_bounds__(256) void select_kernel(
    unsigned* __restrict__ ghist, unsigned* kArr, unsigned* pvalArr, unsigned* gbArr,
    unsigned* v1Arr, unsigned* v2Arr, unsigned* flagArr,
    int shift, unsigned bmask, int nbins, int last) {
  __shared__ unsigned ssum[256], stmp[256];
  __shared__ unsigned sBin, sBelow, sCand[256];
  int tid = threadIdx.x;
  int plane = blockIdx.x;
  unsigned* hp = ghist + (size_t)plane * 2048;
  unsigned k = kArr[plane];
  unsigned lv[8];
  int b0 = tid * 8;
  unsigned lsum = 0;
  #pragma unroll
  for (int j = 0; j < 8; ++j) {
    unsigned c = (b0 + j < nbins) ? hp[b0 + j] : 0u;
    lv[j] = c; lsum += c;
  }
  ssum[tid] = lsum;
  __syncthreads();
  for (int off = 1; off < 256; off <<= 1) {
    stmp[tid] = (tid >= off) ? ssum[tid - off] : 0u; __syncthreads();
    ssum[tid] += stmp[tid]; __syncthreads();
  }
  unsigned incl = ssum[tid], excl = incl - lsum;
  if (excl <= k && k < incl) {
    unsigned kk = k - excl, below = excl;
    #pragma unroll
    for (int j = 0; j < 8; ++j) {
      if (kk < lv[j]) { sBin = (unsigned)(b0 + j); sBelow = below; break; }
      kk -= lv[j]; below += lv[j];
    }
  }
  __syncthreads();
  unsigned bin = sBin, below = sBelow;
  unsigned pvalNew = pvalArr[plane] | (bin << shift);
  unsigned gbNew = gbArr[plane] + below;
  if (!last) {
    for (int i = tid; i < 2048; i += 256) hp[i] = 0u;   // ready for next pass
    if (tid == 0) { kArr[plane] = k - below; pvalArr[plane] = pvalNew; gbArr[plane] = gbNew; }
  } else {
    // pass-3 bins are exact keys within the 22-bit prefix
    unsigned cand = 0xFFFFFFFFu;
    #pragma unroll
    for (int j = 0; j < 8; ++j) {
      int g = b0 + j;
      if (g > (int)bin && g < nbins && lv[j] > 0u && (unsigned)g < cand) cand = (unsigned)g;
    }
    sCand[tid] = cand;
    __syncthreads();
    for (int s = 128; s > 0; s >>= 1) {
      if (tid < s) { unsigned o = sCand[tid + s]; if (o < sCand[tid]) sCand[tid] = o; }
      __syncthreads();
    }
    if (tid == 0) {
      unsigned ceq = hp[bin];      // count of keys == v1key
      v1Arr[plane] = pvalNew;
      if (131072u < gbNew + ceq) {          // rank-131072 inside the equal run
        v2Arr[plane] = pvalNew; flagArr[plane] = 0u;
      } else if (sCand[0] != 0xFFFFFFFFu) { // next key shares the 22-bit prefix
        v2Arr[plane] = (pvalNew & ~(bmask << shift)) | (sCand[0] << shift);
        flagArr[plane] = 0u;
      } else {                              // rare: need global min key > v1key
        v2Arr[plane] = 0xFFFFFFFFu; flagArr[plane] = 1u;
      }
    }
  }
}

__global__ __launch_bounds__(256) void minabove_kernel(
    const float* __restrict__ up, const unsigned* __restrict__ flagArr,
    const unsigned* __restrict__ v1Arr, unsigned* __restrict__ v2Arr) {
  int plane = blockIdx.y, chunk = blockIdx.x, tid = threadIdx.x;
  if (!flagArr[plane]) return;   // usually taken -> near-zero cost
  unsigned v1 = v1Arr[plane];
  const float4* base = reinterpret_cast<const float4*>(up + (size_t)plane * PLANE_ELEMS)
                       + (size_t)chunk * 4096;
  unsigned m = 0xFFFFFFFFu;
  for (int it = 0; it < 16; ++it) {
    float4 v = base[it * 256 + tid];
    unsigned k;
    k = f2key(v.x); if (k > v1 && k < m) m = k;
    k = f2key(v.y); if (k > v1 && k < m) m = k;
    k = f2key(v.z); if (k > v1 && k < m) m = k;
    k = f2key(v.w); if (k > v1 && k < m) m = k;
  }
  for (int off = 32; off > 0; off >>= 1) {
    unsigned o = __shfl_down(m, off, 64);
    if (o < m) m = o;
  }
  if ((tid & 63) == 0) atomicMin(&v2Arr[plane], m);
}

__global__ void finalize_kernel(const unsigned* __restrict__ v1Arr,
                                const unsigned* __restrict__ v2Arr,
                                float* __restrict__ med) {
  int i = threadIdx.x;
  if (i < NPLANE) med[i] = 0.5f * (key2f(v1Arr[i]) + key2f(v2Arr[i]));
}

// ---------- peak pass: rolling-register 3x3 local max + masked sum ----------
__device__ __forceinline__ void row_load(const float* __restrict__ p, int y, int x0,
                                         float4& v, float& l, float& r) {
  if ((unsigned)y >= (unsigned)UP_) {
    float ni = ninf();
    v.x = v.y = v.z = v.w = ni; l = ni; r = ni;
    return;
  }
  const float* row = p + y * UP_ + x0;
  v = *reinterpret_cast<const float4*>(row);
  l = (x0 > 0) ? row[-1] : ninf();
  r = (x0 < UP_ - 4) ? row[4] : ninf();
}
__device__ __forceinline__ float4 hmax4(const float4& v, float l, float r) {
  float4 h;
  h.x = fmaxf(fmaxf(l, v.x), v.y);
  h.y = fmaxf(fmaxf(v.x, v.y), v.z);
  h.z = fmaxf(fmaxf(v.y, v.z), v.w);
  h.w = fmaxf(fmaxf(v.z, v.w), r);
  return h;
}

__global__ __launch_bounds__(256) void peak2_kernel(
    const float* __restrict__ cm, const float* __restrict__ med_arr,
    float* __restrict__ sums, float* __restrict__ cnts) {
  int tid = threadIdx.x;
  int plane = blockIdx.x;                   // 152
  int strip = tid & 127;                    // 128 strips of 4 cols
  int ychunk = blockIdx.y * 2 + (tid >> 7); // 8 chunks of 64 rows
  int x0 = strip * 4;
  int ystart = ychunk * 64;
  const float* p = cm + (size_t)plane * PLANE_ELEMS;
  float med = med_arr[plane];

  float4 v, vn; float l, r;
  row_load(p, ystart - 1, x0, v, l, r);
  float4 hprev = hmax4(v, l, r);
  row_load(p, ystart, x0, v, l, r);
  float4 hcur = hmax4(v, l, r);
  float4 vcur = v;

  float lsum = 0.f; int lcnt = 0;
  for (int yi = 0; yi < 64; ++yi) {
    int y = ystart + yi;
    float ln, rn;
    row_load(p, y + 1, x0, vn, ln, rn);
    float4 hnext = hmax4(vn, ln, rn);
    float mx = fmaxf(fmaxf(hprev.x, hcur.x), hnext.x);
    float my = fmaxf(fmaxf(hprev.y, hcur.y), hnext.y);
    float mz = fmaxf(fmaxf(hprev.z, hcur.z), hnext.z);
    float mw = fmaxf(fmaxf(hprev.w, hcur.w), hnext.w);
    if (vcur.x == mx && vcur.x >= med) { lsum += vcur.x; ++lcnt; }
    if (vcur.y == my && vcur.y >= med) { lsum += vcur.y; ++lcnt; }
    if (vcur.z == mz && vcur.z >= med) { lsum += vcur.z; ++lcnt; }
    if (vcur.w == mw && vcur.w >= med) { lsum += vcur.w; ++lcnt; }
    hprev = hcur; hcur = hnext; vcur = vn;
  }

  __shared__ float ss[256];
  __shared__ int sc[256];
  ss[tid] = lsum; sc[tid] = lcnt;
  __syncthreads();
  for (int s = 128; s > 0; s >>= 1) {
    if (tid < s) { ss[tid] += ss[tid + s]; sc[tid] += sc[tid + s]; }
    __syncthreads();
  }
  if (tid == 0) {
    atomicAdd(&sums[plane], ss[0]);
    atomicAdd(&cnts[plane], (float)sc[0]);
  }
}

__global__ void logits_kernel(const float* __restrict__ sums,
                              const float* __restrict__ cnts,
                              float* __restrict__ out) {
  int i = threadIdx.x;
  if (i < NPLANE) out[i] = sums[i] / cnts[i];
}

// ---------- launch ----------
extern "C" void kernel_launch(void* const* d_in, const int* in_sizes, int n_in,
                              void* d_out, int out_size, void* d_ws, size_t ws_size,
                              hipStream_t stream) {
  const float* x  = (const float*)d_in[0];
  const float* w1 = (const float*)d_in[1];
  const float* b1 = (const float*)d_in[2];
  const float* w2 = (const float*)d_in[3];
  const float* b2 = (const float*)d_in[4];
  float* out = (float*)d_out;

  float* ws = (float*)d_ws;
  float* c0 = ws;                                      // 9,961,472 floats
  unsigned* hist    = (unsigned*)(ws + 9961472);       // 152*2048 = 311,296
  unsigned* kArr    = hist + 311296;
  unsigned* pvalArr = kArr + NPLANE;
  unsigned* gbArr   = pvalArr + NPLANE;
  unsigned* v1Arr   = gbArr + NPLANE;
  unsigned* v2Arr   = v1Arr + NPLANE;
  unsigned* flagArr = v2Arr + NPLANE;
  float* med  = (float*)(flagArr + NPLANE);
  float* sums = med + NPLANE;
  float* cnts = sums + NPLANE;
  float* h = out;   // conv1 scratch; fully overwritten by upsample

  init_kernel<<<1, 256, 0, stream>>>(kArr, pvalArr, gbArr, flagArr);
  hipMemsetAsync(hist, 0, (size_t)NPLANE * 2048 * sizeof(unsigned), stream);
  hipMemsetAsync(sums, 0, 2 * NPLANE * sizeof(float), stream);

  conv1_kernel<<<dim3(64, 2, 8), 256, 0, stream>>>(x, w1, b1, h);
  conv2_kernel<<<dim3(64, 2, 8), 256, 0, stream>>>(h, w2, b2, c0);

  // upsample + median hist pass 1 (bits 31:21) fused
  upsample_hist_kernel<<<dim3(8, NPLANE), 256, 0, stream>>>(c0, out, hist);
  select_kernel<<<dim3(NPLANE), 256, 0, stream>>>(hist, kArr, pvalArr, gbArr,
      v1Arr, v2Arr, flagArr, 21, 0x7FFu, 2048, 0);
  hist_pass_kernel<<<dim3(8, NPLANE), 256, 0, stream>>>(out, pvalArr, hist, 10, 0x7FFu, 0xFFE00000u);
  select_kernel<<<dim3(NPLANE), 256, 0, stream>>>(hist, kArr, pvalArr, gbArr,
      v1Arr, v2Arr, flagArr, 10, 0x7FFu, 2048, 0);
  hist_pass_kernel<<<dim3(8, NPLANE), 256, 0, stream>>>(out, pvalArr, hist, 0, 0x3FFu, 0xFFFFFC00u);
  select_kernel<<<dim3(NPLANE), 256, 0, stream>>>(hist, kArr, pvalArr, gbArr,
      v1Arr, v2Arr, flagArr, 0, 0x3FFu, 1024, 1);
  minabove_kernel<<<dim3(16, NPLANE), 256, 0, stream>>>(out, flagArr, v1Arr, v2Arr);
  finalize_kernel<<<1, 256, 0, stream>>>(v1Arr, v2Arr, med);

  peak2_kernel<<<dim3(NPLANE, 4), 256, 0, stream>>>(out, med, sums, cnts);
  logits_kernel<<<1, 192, 0, stream>>>(sums, cnts, out + (out_size - NPLANE));
}

// Round 9
// 502.987 us; speedup vs baseline: 6.2197x; 6.2197x over previous
//
#include <hip/hip_runtime.h>

#define B_ 8
#define CIN_ 4
#define H_ 512
#define W_ 512
#define HID_ 32
#define NCLS_ 19
#define HO_ 256
#define WO_ 256
#define UP_ 512
#define NPLANE (B_*NCLS_)          // 152
#define PLANE_ELEMS (UP_*UP_)      // 262144
#define KMED1 131071u

// ---------- helpers ----------

__device__ __forceinline__ unsigned f2key(float f) {
  unsigned u = __float_as_uint(f);
  return (u & 0x80000000u) ? ~u : (u | 0x80000000u);
}
__device__ __forceinline__ float key2f(unsigned k) {
  unsigned u = (k & 0x80000000u) ? (k & 0x7FFFFFFFu) : ~k;
  return __uint_as_float(u);
}
__device__ __forceinline__ float ninf() { return __uint_as_float(0xFF800000u); }

// Bilinear upsample value (fmaf-pinned so all kernels agree bit-exactly).
__device__ __forceinline__ float up_val(const float* __restrict__ p, int oy, int ox) {
  const float s = (float)(255.0 / 511.0);
  float posy = (float)oy * s;
  int ly = (int)posy; if (ly > 254) ly = 254;
  float fy = posy - (float)ly;
  float posx = (float)ox * s;
  int lx = (int)posx; if (lx > 254) lx = 254;
  float fx = posx - (float)lx;
  const float* q = p + ly * WO_ + lx;
  float a = q[0], b = q[1], c = q[WO_], d = q[WO_ + 1];
  float r0 = fmaf(fx, b - a, a);
  float r1 = fmaf(fx, d - c, c);
  return fmaf(fy, r1 - r0, r0);
}

// ---------- conv1: (8,4,512,512) -> relu -> (8,32,256,256), stride 2, pad 1 ----------
// Round-6 configuration: 2 cols/thread, float2 acc[32], bounds(256,4),
// 1024 blocks. (oc-split x2 regressed: 4x HBM amplification from partial-line
// writes; manual ci-pipelining regressed: scratch spill. Keep this body.)
__global__ __launch_bounds__(256, 4) void conv1_kernel(
    const float* __restrict__ x, const float* __restrict__ w1,
    const float* __restrict__ b1, float* __restrict__ h) {
  int t = threadIdx.x & 63;
  int r = threadIdx.x >> 6;
  int oh = blockIdx.x * 4 + r;
  int b  = blockIdx.z;
  int ow0 = blockIdx.y * 128 + t * 2;
  int ic0 = 2 * ow0;            // center input col of acc.x

  float2 acc[HID_];
  #pragma unroll
  for (int oc = 0; oc < HID_; ++oc) {
    float bb = b1[oc];
    acc[oc].x = bb; acc[oc].y = bb;
  }

  #pragma unroll
  for (int ci = 0; ci < CIN_; ++ci) {
    const float* xp = x + ((size_t)(b * CIN_ + ci)) * H_ * W_;
    float4 A0, A1, A2;
    float lm[3];
    #pragma unroll
    for (int kh = 0; kh < 3; ++kh) {
      int ih = 2 * oh + kh - 1;
      float4 Av; float lv = 0.f;
      if ((unsigned)ih < (unsigned)H_) {
        const float* row = xp + ih * W_;
        Av = *reinterpret_cast<const float4*>(row + ic0);
        lv = (ic0 > 0) ? row[ic0 - 1] : 0.f;
      } else {
        Av.x = 0.f; Av.y = 0.f; Av.z = 0.f; Av.w = 0.f;
      }
      if (kh == 0) A0 = Av; else if (kh == 1) A1 = Av; else A2 = Av;
      lm[kh] = lv;
    }
    #pragma unroll
    for (int oc = 0; oc < HID_; ++oc) {
      const float* wp = w1 + ((size_t)oc * CIN_ + ci) * 9;
      {
        float w0 = wp[0], w1v = wp[1], w2v = wp[2];
        acc[oc].x += w0 * lm[0] + w1v * A0.x + w2v * A0.y;
        acc[oc].y += w0 * A0.y  + w1v * A0.z + w2v * A0.w;
      }
      {
        float w0 = wp[3], w1v = wp[4], w2v = wp[5];
        acc[oc].x += w0 * lm[1] + w1v * A1.x + w2v * A1.y;
        acc[oc].y += w0 * A1.y  + w1v * A1.z + w2v * A1.w;
      }
      {
        float w0 = wp[6], w1v = wp[7], w2v = wp[8];
        acc[oc].x += w0 * lm[2] + w1v * A2.x + w2v * A2.y;
        acc[oc].y += w0 * A2.y  + w1v * A2.z + w2v * A2.w;
      }
    }
  }
  #pragma unroll
  for (int oc = 0; oc < HID_; ++oc) {
    float2 o;
    o.x = fmaxf(acc[oc].x, 0.f); o.y = fmaxf(acc[oc].y, 0.f);
    *reinterpret_cast<float2*>(h + (((size_t)(b * HID_ + oc) * HO_ + oh) * WO_ + ow0)) = o;
  }
}

// ---------- conv2: (8,32,256,256) -> (8,19,256,256), stride 1, pad 1 ----------
// Round-6 body EXACTLY (106 us, VGPR 40, no spill). Manual double-buffer
// pipelining (round 8) spilled to scratch: FETCH 49 MiB -> 5 GB. Reverted.
__global__ __launch_bounds__(256, 4) void conv2_kernel(
    const float* __restrict__ h, const float* __restrict__ w2,
    const float* __restrict__ b2, float* __restrict__ c0) {
  int t = threadIdx.x & 63;
  int r = threadIdx.x >> 6;
  int oh = blockIdx.x * 4 + r;
  int b  = blockIdx.z;
  int ow0 = blockIdx.y * 128 + t * 2;

  float2 acc[NCLS_];
  #pragma unroll
  for (int oc = 0; oc < NCLS_; ++oc) {
    float bb = b2[oc];
    acc[oc].x = bb; acc[oc].y = bb;
  }

  for (int ci = 0; ci < HID_; ++ci) {
    const float* hp = h + ((size_t)(b * HID_ + ci)) * HO_ * WO_;
    float2 M0, M1, M2;
    float L[3], R[3];
    #pragma unroll
    for (int kh = 0; kh < 3; ++kh) {
      int ih = oh + kh - 1;
      float2 Mv;
      float lv = 0.f, rv = 0.f;
      if ((unsigned)ih < (unsigned)HO_) {
        const float* row = hp + ih * WO_;
        Mv = *reinterpret_cast<const float2*>(row + ow0);
        lv = (ow0 > 0) ? row[ow0 - 1] : 0.f;
        rv = (ow0 + 2 < WO_) ? row[ow0 + 2] : 0.f;
      } else {
        Mv.x = 0.f; Mv.y = 0.f;
      }
      if (kh == 0) M0 = Mv; else if (kh == 1) M1 = Mv; else M2 = Mv;
      L[kh] = lv; R[kh] = rv;
    }
    const float* wpc = w2 + ci * 9;
    #pragma unroll
    for (int oc = 0; oc < NCLS_; ++oc) {
      const float* wp = wpc + oc * (HID_ * 9);
      {
        float w0 = wp[0], w1v = wp[1], w2v = wp[2];
        acc[oc].x += w0 * L[0]  + w1v * M0.x + w2v * M0.y;
        acc[oc].y += w0 * M0.x + w1v * M0.y + w2v * R[0];
      }
      {
        float w0 = wp[3], w1v = wp[4], w2v = wp[5];
        acc[oc].x += w0 * L[1]  + w1v * M1.x + w2v * M1.y;
        acc[oc].y += w0 * M1.x + w1v * M1.y + w2v * R[1];
      }
      {
        float w0 = wp[6], w1v = wp[7], w2v = wp[8];
        acc[oc].x += w0 * L[2]  + w1v * M2.x + w2v * M2.y;
        acc[oc].y += w0 * M2.x + w1v * M2.y + w2v * R[2];
      }
    }
  }
  #pragma unroll
  for (int oc = 0; oc < NCLS_; ++oc) {
    *reinterpret_cast<float2*>(c0 + (((size_t)(b * NCLS_ + oc) * HO_ + oh) * WO_ + ow0)) = acc[oc];
  }
}

// ---------- upsample fused with median hist pass 1 ----------
// grid (8 chunks of 64 rows, 152 planes). Computes the bilinear plane, stores
// it, and histograms key>>21 (pass-1 fmask=0 -> unconditional) into the same
// wave-privatized LDS layout the standalone pass used. Eliminates one full
// 159 MB plane read + one launch; merge traffic unchanged (8x2048/plane).
__global__ __launch_bounds__(256) void upsample_hist_kernel(
    const float* __restrict__ c0, float* __restrict__ out,
    unsigned* __restrict__ ghist) {
  __shared__ unsigned lh[4 * 2048];
  int tid = threadIdx.x;
  int chunk = blockIdx.x;
  int plane = blockIdx.y;
  unsigned* mylh = lh + ((tid >> 6) << 11);
  for (int i = tid; i < 4 * 2048; i += 256) lh[i] = 0u;
  __syncthreads();
  const float* p = c0 + (size_t)plane * HO_ * WO_;
  float* op = out + (size_t)plane * PLANE_ELEMS;
  int ox0 = (tid & 127) * 4;
  #pragma unroll 2
  for (int it = 0; it < 32; ++it) {
    int oy = chunk * 64 + it * 2 + (tid >> 7);
    float4 o;
    o.x = up_val(p, oy, ox0 + 0);
    o.y = up_val(p, oy, ox0 + 1);
    o.z = up_val(p, oy, ox0 + 2);
    o.w = up_val(p, oy, ox0 + 3);
    *reinterpret_cast<float4*>(op + (size_t)oy * UP_ + ox0) = o;
    atomicAdd(&mylh[f2key(o.x) >> 21], 1u);
    atomicAdd(&mylh[f2key(o.y) >> 21], 1u);
    atomicAdd(&mylh[f2key(o.z) >> 21], 1u);
    atomicAdd(&mylh[f2key(o.w) >> 21], 1u);
  }
  __syncthreads();
  for (int i = tid; i < 2048; i += 256) {
    unsigned c = lh[i] + lh[2048 + i] + lh[4096 + i] + lh[6144 + i];
    if (c) atomicAdd(&ghist[(size_t)plane * 2048 + i], c);
  }
}

// ---------- median machinery: radix select over the materialized plane ----------

__global__ void init_kernel(unsigned* kArr, unsigned* pvalArr, unsigned* gbArr,
                            unsigned* flagArr) {
  int i = threadIdx.x;
  if (i < NPLANE) { kArr[i] = KMED1; pvalArr[i] = 0u; gbArr[i] = 0u; flagArr[i] = 0u; }
}

// Passes 2 & 3: coalesced float4 reads of the materialized plane (L3-hot).
__global__ __launch_bounds__(256) void hist_pass_kernel(
    const float* __restrict__ up, const unsigned* __restrict__ pvalArr,
    unsigned* __restrict__ ghist, int shift, unsigned bmask, unsigned fmask) {
  __shared__ unsigned lh[4 * 2048];
  int tid = threadIdx.x;
  int chunk = blockIdx.x;   // 8 chunks of 32768 elements
  int plane = blockIdx.y;
  unsigned* mylh = lh + ((tid >> 6) << 11);
  for (int i = tid; i < 4 * 2048; i += 256) lh[i] = 0u;
  __syncthreads();
  unsigned fval = pvalArr[plane] & fmask;
  const float4* p4 = reinterpret_cast<const float4*>(up + (size_t)plane * PLANE_ELEMS)
                     + (size_t)chunk * 8192;
  #pragma unroll 4
  for (int it = 0; it < 32; ++it) {
    float4 v = p4[it * 256 + tid];
    unsigned k0 = f2key(v.x), k1 = f2key(v.y), k2 = f2key(v.z), k3 = f2key(v.w);
    if ((k0 & fmask) == fval) atomicAdd(&mylh[(k0 >> shift) & bmask], 1u);
    if ((k1 & fmask) == fval) atomicAdd(&mylh[(k1 >> shift) & bmask], 1u);
    if ((k2 & fmask) == fval) atomicAdd(&mylh[(k2 >> shift) & bmask], 1u);
    if ((k3 & fmask) == fval) atomicAdd(&mylh[(k3 >> shift) & bmask], 1u);
  }
  __syncthreads();
  for (int i = tid; i < 2048; i += 256) {
    unsigned c = lh[i] + lh[2048 + i] + lh[4096 + i] + lh[6144 + i];
    if (c) atomicAdd(&ghist[(size_t)plane * 2048 + i], c);
  }
}

__global__ __launch_bounds__(256) void select_kernel(
    unsigned* __restrict__ ghist, unsigned* kArr, unsigned* pvalArr, unsigned* gbArr,
    unsigned* v1Arr, unsigned* v2Arr, unsigned* flagArr,
    int shift, unsigned bmask, int nbins, int last) {
  __shared__ unsigned ssum[256], stmp[256];
  __shared__ unsigned sBin, sBelow, sCand[256];
  int tid = threadIdx.x;
  int plane = blockIdx.x;
  unsigned* hp = ghist + (size_t)plane * 2048;
  unsigned k = kArr[plane];
  unsigned lv[8];
  int b0 = tid * 8;
  unsigned lsum = 0;
  #pragma unroll
  for (int j = 0; j < 8; ++j) {
    unsigned c = (b0 + j < nbins) ? hp[b0 + j] : 0u;
    lv[j] = c; lsum += c;
  }
  ssum[tid] = lsum;
  __syncthreads();
  for (int off = 1; off < 256; off <<= 1) {
    stmp[tid] = (tid >= off) ? ssum[tid - off] : 0u; __syncthreads();
    ssum[tid] += stmp[tid]; __syncthreads();
  }
  unsigned incl = ssum[tid], excl = incl - lsum;
  if (excl <= k && k < incl) {
    unsigned kk = k - excl, below = excl;
    #pragma unroll
    for (int j = 0; j < 8; ++j) {
      if (kk < lv[j]) { sBin = (unsigned)(b0 + j); sBelow = below; break; }
      kk -= lv[j]; below += lv[j];
    }
  }
  __syncthreads();
  unsigned bin = sBin, below = sBelow;
  unsigned pvalNew = pvalArr[plane] | (bin << shift);
  unsigned gbNew = gbArr[plane] + below;
  if (!last) {
    for (int i = tid; i < 2048; i += 256) hp[i] = 0u;   // ready for next pass
    if (tid == 0) { kArr[plane] = k - below; pvalArr[plane] = pvalNew; gbArr[plane] = gbNew; }
  } else {
    // pass-3 bins are exact keys within the 22-bit prefix
    unsigned cand = 0xFFFFFFFFu;
    #pragma unroll
    for (int j = 0; j < 8; ++j) {
      int g = b0 + j;
      if (g > (int)bin && g < nbins && lv[j] > 0u && (unsigned)g < cand) cand = (unsigned)g;
    }
    sCand[tid] = cand;
    __syncthreads();
    for (int s = 128; s > 0; s >>= 1) {
      if (tid < s) { unsigned o = sCand[tid + s]; if (o < sCand[tid]) sCand[tid] = o; }
      __syncthreads();
    }
    if (tid == 0) {
      unsigned ceq = hp[bin];      // count of keys == v1key
      v1Arr[plane] = pvalNew;
      if (131072u < gbNew + ceq) {          // rank-131072 inside the equal run
        v2Arr[plane] = pvalNew; flagArr[plane] = 0u;
      } else if (sCand[0] != 0xFFFFFFFFu) { // next key shares the 22-bit prefix
        v2Arr[plane] = (pvalNew & ~(bmask << shift)) | (sCand[0] << shift);
        flagArr[plane] = 0u;
      } else {                              // rare: need global min key > v1key
        v2Arr[plane] = 0xFFFFFFFFu; flagArr[plane] = 1u;
      }
    }
  }
}

__global__ __launch_bounds__(256) void minabove_kernel(
    const float* __restrict__ up, const unsigned* __restrict__ flagArr,
    const unsigned* __restrict__ v1Arr, unsigned* __restrict__ v2Arr) {
  int plane = blockIdx.y, chunk = blockIdx.x, tid = threadIdx.x;
  if (!flagArr[plane]) return;   // usually taken -> near-zero cost
  unsigned v1 = v1Arr[plane];
  const float4* base = reinterpret_cast<const float4*>(up + (size_t)plane * PLANE_ELEMS)
                       + (size_t)chunk * 4096;
  unsigned m = 0xFFFFFFFFu;
  for (int it = 0; it < 16; ++it) {
    float4 v = base[it * 256 + tid];
    unsigned k;
    k = f2key(v.x); if (k > v1 && k < m) m = k;
    k = f2key(v.y); if (k > v1 && k < m) m = k;
    k = f2key(v.z); if (k > v1 && k < m) m = k;
    k = f2key(v.w); if (k > v1 && k < m) m = k;
  }
  for (int off = 32; off > 0; off >>= 1) {
    unsigned o = __shfl_down(m, off, 64);
    if (o < m) m = o;
  }
  if ((tid & 63) == 0) atomicMin(&v2Arr[plane], m);
}

__global__ void finalize_kernel(const unsigned* __restrict__ v1Arr,
                                const unsigned* __restrict__ v2Arr,
                                float* __restrict__ med) {
  int i = threadIdx.x;
  if (i < NPLANE) med[i] = 0.5f * (key2f(v1Arr[i]) + key2f(v2Arr[i]));
}

// ---------- peak pass: rolling-register 3x3 local max + masked sum ----------
__device__ __forceinline__ void row_load(const float* __restrict__ p, int y, int x0,
                                         float4& v, float& l, float& r) {
  if ((unsigned)y >= (unsigned)UP_) {
    float ni = ninf();
    v.x = v.y = v.z = v.w = ni; l = ni; r = ni;
    return;
  }
  const float* row = p + y * UP_ + x0;
  v = *reinterpret_cast<const float4*>(row);
  l = (x0 > 0) ? row[-1] : ninf();
  r = (x0 < UP_ - 4) ? row[4] : ninf();
}
__device__ __forceinline__ float4 hmax4(const float4& v, float l, float r) {
  float4 h;
  h.x = fmaxf(fmaxf(l, v.x), v.y);
  h.y = fmaxf(fmaxf(v.x, v.y), v.z);
  h.z = fmaxf(fmaxf(v.y, v.z), v.w);
  h.w = fmaxf(fmaxf(v.z, v.w), r);
  return h;
}

__global__ __launch_bounds__(256) void peak2_kernel(
    const float* __restrict__ cm, const float* __restrict__ med_arr,
    float* __restrict__ sums, float* __restrict__ cnts) {
  int tid = threadIdx.x;
  int plane = blockIdx.x;                   // 152
  int strip = tid & 127;                    // 128 strips of 4 cols
  int ychunk = blockIdx.y * 2 + (tid >> 7); // 8 chunks of 64 rows
  int x0 = strip * 4;
  int ystart = ychunk * 64;
  const float* p = cm + (size_t)plane * PLANE_ELEMS;
  float med = med_arr[plane];

  float4 v, vn; float l, r;
  row_load(p, ystart - 1, x0, v, l, r);
  float4 hprev = hmax4(v, l, r);
  row_load(p, ystart, x0, v, l, r);
  float4 hcur = hmax4(v, l, r);
  float4 vcur = v;

  float lsum = 0.f; int lcnt = 0;
  for (int yi = 0; yi < 64; ++yi) {
    int y = ystart + yi;
    float ln, rn;
    row_load(p, y + 1, x0, vn, ln, rn);
    float4 hnext = hmax4(vn, ln, rn);
    float mx = fmaxf(fmaxf(hprev.x, hcur.x), hnext.x);
    float my = fmaxf(fmaxf(hprev.y, hcur.y), hnext.y);
    float mz = fmaxf(fmaxf(hprev.z, hcur.z), hnext.z);
    float mw = fmaxf(fmaxf(hprev.w, hcur.w), hnext.w);
    if (vcur.x == mx && vcur.x >= med) { lsum += vcur.x; ++lcnt; }
    if (vcur.y == my && vcur.y >= med) { lsum += vcur.y; ++lcnt; }
    if (vcur.z == mz && vcur.z >= med) { lsum += vcur.z; ++lcnt; }
    if (vcur.w == mw && vcur.w >= med) { lsum += vcur.w; ++lcnt; }
    hprev = hcur; hcur = hnext; vcur = vn;
  }

  __shared__ float ss[256];
  __shared__ int sc[256];
  ss[tid] = lsum; sc[tid] = lcnt;
  __syncthreads();
  for (int s = 128; s > 0; s >>= 1) {
    if (tid < s) { ss[tid] += ss[tid + s]; sc[tid] += sc[tid + s]; }
    __syncthreads();
  }
  if (tid == 0) {
    atomicAdd(&sums[plane], ss[0]);
    atomicAdd(&cnts[plane], (float)sc[0]);
  }
}

__global__ void logits_kernel(const float* __restrict__ sums,
                              const float* __restrict__ cnts,
                              float* __restrict__ out) {
  int i = threadIdx.x;
  if (i < NPLANE) out[i] = sums[i] / cnts[i];
}

// ---------- launch ----------
extern "C" void kernel_launch(void* const* d_in, const int* in_sizes, int n_in,
                              void* d_out, int out_size, void* d_ws, size_t ws_size,
                              hipStream_t stream) {
  const float* x  = (const float*)d_in[0];
  const float* w1 = (const float*)d_in[1];
  const float* b1 = (const float*)d_in[2];
  const float* w2 = (const float*)d_in[3];
  const float* b2 = (const float*)d_in[4];
  float* out = (float*)d_out;

  float* ws = (float*)d_ws;
  float* c0 = ws;                                      // 9,961,472 floats
  unsigned* hist    = (unsigned*)(ws + 9961472);       // 152*2048 = 311,296
  unsigned* kArr    = hist + 311296;
  unsigned* pvalArr = kArr + NPLANE;
  unsigned* gbArr   = pvalArr + NPLANE;
  unsigned* v1Arr   = gbArr + NPLANE;
  unsigned* v2Arr   = v1Arr + NPLANE;
  unsigned* flagArr = v2Arr + NPLANE;
  float* med  = (float*)(flagArr + NPLANE);
  float* sums = med + NPLANE;
  float* cnts = sums + NPLANE;
  float* h = out;   // conv1 scratch; fully overwritten by upsample

  init_kernel<<<1, 256, 0, stream>>>(kArr, pvalArr, gbArr, flagArr);
  hipMemsetAsync(hist, 0, (size_t)NPLANE * 2048 * sizeof(unsigned), stream);
  hipMemsetAsync(sums, 0, 2 * NPLANE * sizeof(float), stream);

  conv1_kernel<<<dim3(64, 2, 8), 256, 0, stream>>>(x, w1, b1, h);
  conv2_kernel<<<dim3(64, 2, 8), 256, 0, stream>>>(h, w2, b2, c0);

  // upsample + median hist pass 1 (bits 31:21) fused
  upsample_hist_kernel<<<dim3(8, NPLANE), 256, 0, stream>>>(c0, out, hist);
  select_kernel<<<dim3(NPLANE), 256, 0, stream>>>(hist, kArr, pvalArr, gbArr,
      v1Arr, v2Arr, flagArr, 21, 0x7FFu, 2048, 0);
  hist_pass_kernel<<<dim3(8, NPLANE), 256, 0, stream>>>(out, pvalArr, hist, 10, 0x7FFu, 0xFFE00000u);
  select_kernel<<<dim3(NPLANE), 256, 0, stream>>>(hist, kArr, pvalArr, gbArr,
      v1Arr, v2Arr, flagArr, 10, 0x7FFu, 2048, 0);
  hist_pass_kernel<<<dim3(8, NPLANE), 256, 0, stream>>>(out, pvalArr, hist, 0, 0x3FFu, 0xFFFFFC00u);
  select_kernel<<<dim3(NPLANE), 256, 0, stream>>>(hist, kArr, pvalArr, gbArr,
      v1Arr, v2Arr, flagArr, 0, 0x3FFu, 1024, 1);
  minabove_kernel<<<dim3(16, NPLANE), 256, 0, stream>>>(out, flagArr, v1Arr, v2Arr);
  finalize_kernel<<<1, 256, 0, stream>>>(v1Arr, v2Arr, med);

  peak2_kernel<<<dim3(NPLANE, 4), 256, 0, stream>>>(out, med, sums, cnts);
  logits_kernel<<<1, 192, 0, stream>>>(sums, cnts, out + (out_size - NPLANE));
}